// Round 8
// baseline (111.046 us; speedup 1.0000x reference)
//
#include <hip/hip_runtime.h>
#include <hip/hip_bf16.h>

#define BATCH  512
#define IN_F   4096
#define OUT_F  4096
#define CAP    208     // bucket capacity; Poisson(122), overflow prob ~1e-11/row

typedef __attribute__((ext_vector_type(8))) short bf16x8;   // 8 bf16 = 4 VGPR (MFMA A/B frag)
typedef __attribute__((ext_vector_type(4))) float f32x4;    // MFMA C/D frag

// bf16 round-to-nearest-even bits from fp32
__device__ __forceinline__ unsigned bf16_bits(float f) {
    unsigned u = __float_as_uint(f);
    return (u + 0x7FFFu + ((u >> 16) & 1u)) >> 16;
}

// ---------------- 1) scatter entries into fixed-capacity row buckets ----------------
// packed[r*CAP + k] = (bf16(w) << 16) | col   (col fits 12 bits)
__global__ void scatter_pairs_kernel(const int* __restrict__ rows,
                                     const int* __restrict__ cols,
                                     const float* __restrict__ w,
                                     int nnz,
                                     int* __restrict__ counts,
                                     unsigned* __restrict__ pairs) {
    int i = blockIdx.x * blockDim.x + threadIdx.x;
    int i4 = i * 4;
    if (i4 + 4 <= nnz) {
        int4   r  = ((const int4*)rows)[i];
        int4   c  = ((const int4*)cols)[i];
        float4 wv = ((const float4*)w)[i];
        int p0 = atomicAdd(&counts[r.x], 1);
        if (p0 < CAP) pairs[(size_t)r.x * CAP + p0] = (bf16_bits(wv.x) << 16) | (unsigned)c.x;
        int p1 = atomicAdd(&counts[r.y], 1);
        if (p1 < CAP) pairs[(size_t)r.y * CAP + p1] = (bf16_bits(wv.y) << 16) | (unsigned)c.y;
        int p2 = atomicAdd(&counts[r.z], 1);
        if (p2 < CAP) pairs[(size_t)r.z * CAP + p2] = (bf16_bits(wv.z) << 16) | (unsigned)c.z;
        int p3 = atomicAdd(&counts[r.w], 1);
        if (p3 < CAP) pairs[(size_t)r.w * CAP + p3] = (bf16_bits(wv.w) << 16) | (unsigned)c.w;
    } else {
        for (int j = i4; j < nnz; ++j) {
            int rr = rows[j];
            int pp = atomicAdd(&counts[rr], 1);
            if (pp < CAP) pairs[(size_t)rr * CAP + pp] = (bf16_bits(w[j]) << 16) | (unsigned)cols[j];
        }
    }
}

// ---------------- 2) densify: one block per output row -> bf16 dense W (N,K) ----------------
__global__ __launch_bounds__(256) void densify_rows_kernel(const unsigned* __restrict__ pairs,
                                                           const int* __restrict__ counts,
                                                           __hip_bfloat16* __restrict__ Wb) {
    __shared__ __align__(16) float row[IN_F];   // 16 KB
    const int r = blockIdx.x;
    const int t = threadIdx.x;
    const float4 z = make_float4(0.f, 0.f, 0.f, 0.f);
#pragma unroll
    for (int k = 0; k < IN_F / 4 / 256; ++k)
        ((float4*)row)[t + k * 256] = z;
    __syncthreads();
    int cnt = counts[r];
    if (cnt > CAP) cnt = CAP;
    const unsigned* bucket = pairs + (size_t)r * CAP;
    for (int j = t; j < cnt; j += 256) {
        unsigned p = bucket[j];
        atomicAdd(&row[p & 0xFFFu], __uint_as_float(p & 0xFFFF0000u));
    }
    __syncthreads();
    unsigned* dst = (unsigned*)(Wb + (size_t)r * IN_F);
#pragma unroll
    for (int k = 0; k < (IN_F / 2) / 256; ++k) {
        int ui = t + k * 256;
        unsigned lo = bf16_bits(row[ui * 2]);
        unsigned hi = bf16_bits(row[ui * 2 + 1]);
        dst[ui] = lo | (hi << 16);
    }
}

// ---------------- 3) convert x fp32 -> bf16  +  init out with bias ----------------
__global__ void convert_bias_kernel(const float* __restrict__ x, __hip_bfloat16* __restrict__ xb,
                                    const float* __restrict__ bias, float* __restrict__ out) {
    const int NC = BATCH * IN_F / 4;
    int i = blockIdx.x * blockDim.x + threadIdx.x;
    if (i < NC) {
        float4 v = ((const float4*)x)[i];
        unsigned lo = bf16_bits(v.x) | (bf16_bits(v.y) << 16);
        unsigned hi = bf16_bits(v.z) | (bf16_bits(v.w) << 16);
        ((uint2*)xb)[i] = make_uint2(lo, hi);
    } else {
        int j = i - NC;                                   // indexes out as float4
        ((float4*)out)[j] = ((const float4*)bias)[j & (OUT_F / 4 - 1)];
    }
}

// ---------------- 4) GEMM: out[b,n] += sum_k xb[b,k]*Wb[n,k]  (K-split=4) ----------------
// BM=BN=128 tile, 4 waves (2x2), each wave owns a 64x64 output (4x4 16x16 frags) ->
// LDS-read:MFMA = 1:2 (vs 1:1 at 64x64 tiles). KSPLIT=4 -> 512 blocks = 2 blocks/CU
// (LDS 64 KB/block). Counted-vmcnt raw-barrier pipeline: prefetch loads stay in
// flight across barriers (no vmcnt(0) drain in steady state). The 4 ksp partners of
// each (m,n) tile map to the SAME XCD so the atomic epilogue stays in one L2.
#define BM  128
#define BN  128
#define BKT 64
#define KSPLIT 4
#define KH   (IN_F / KSPLIT)            // 1024
#define NKTH (KH / BKT)                 // 16
#define NWG  ((BATCH / BM) * (OUT_F / BN) * KSPLIT)   // 512

__global__ __launch_bounds__(256) void gemm_acc_kernel(
    const __hip_bfloat16* __restrict__ xb,   // (512, 4096) row-major
    const __hip_bfloat16* __restrict__ Wb,   // (4096, 4096) = (N, K) row-major
    float* __restrict__ out) {               // (512, 4096) fp32, pre-filled with bias

    __shared__ __align__(16) __hip_bfloat16 As[2][BM][BKT];   // 32 KB
    __shared__ __align__(16) __hip_bfloat16 Bs[2][BN][BKT];   // 32 KB

    // XCD-grouped decomposition: blockIdx&7 ~ XCD; each XCD chunk holds all 4 ksp
    // of 16 (m,n) tiles -> K-split atomics stay within one XCD's L2.
    const int xcd   = blockIdx.x & 7;
    const int local = blockIdx.x >> 3;        // 0..63
    const int ksp   = local & 3;
    const int tile  = xcd * 16 + (local >> 2); // 0..127
    const int bm0   = (tile & 3) * BM;
    const int bn0   = (tile >> 2) * BN;
    const size_t k0 = (size_t)ksp * KH;

    const int t  = threadIdx.x;
    const int l  = t & 63;
    const int w  = t >> 6;
    const int wr = w >> 1;        // wave row 0..1 (64-row strip)
    const int wc = w & 1;         // wave col 0..1 (64-col strip)
    const int lr = l & 15;        // frag lane
    const int lg = l >> 4;        // k-group 0..3

    f32x4 acc[4][4] = {};

    // stage K-tile kt into buffer p: A 1024 16B-chunks + B 1024 (8 gload_lds/thread).
    // chunk q: row=q>>3, slot s=q&7 holds global k-chunk s^(row&7) (pre-swizzled source
    // so the linear LDS dest of global_load_lds yields conflict-free ds_read_b128).
#define STAGE(p, kt) do {                                                                         \
    _Pragma("unroll")                                                                             \
    for (int j = 0; j < 4; ++j) {                                                                 \
        int q = t + j * 256; int row = q >> 3; int kcg = (q & 7) ^ (row & 7);                     \
        __builtin_amdgcn_global_load_lds(                                                         \
            (const unsigned*)(xb + (size_t)(bm0 + row) * IN_F + k0 + (kt) * BKT + kcg * 8),       \
            (unsigned*)((__hip_bfloat16*)As[p] + q * 8), 16, 0, 0);                               \
    }                                                                                             \
    _Pragma("unroll")                                                                             \
    for (int j = 0; j < 4; ++j) {                                                                 \
        int q = t + j * 256; int row = q >> 3; int kcg = (q & 7) ^ (row & 7);                     \
        __builtin_amdgcn_global_load_lds(                                                         \
            (const unsigned*)(Wb + (size_t)(bn0 + row) * IN_F + k0 + (kt) * BKT + kcg * 8),       \
            (unsigned*)((__hip_bfloat16*)Bs[p] + q * 8), 16, 0, 0);                               \
    }                                                                                             \
} while (0)

    const int rowA0 = wr * 64 + lr;
    const int rowB0 = wc * 64 + lr;
    const int xA = rowA0 & 7;     // rows rowA0+16i keep the same &7
    const int xB = rowB0 & 7;

    STAGE(0, 0);
    for (int kt = 0; kt < NKTH; ++kt) {
        const int p = kt & 1;
        if (kt + 1 < NKTH) {
            STAGE(p ^ 1, kt + 1);                              // 8 more loads in flight
            asm volatile("s_waitcnt vmcnt(8)" ::: "memory");   // kt's 8 landed; kt+1's fly on
        } else {
            asm volatile("s_waitcnt vmcnt(0)" ::: "memory");   // final tile: full drain
        }
        __builtin_amdgcn_s_barrier();                          // all waves: tile kt ready

#pragma unroll
        for (int ks = 0; ks < 2; ++ks) {
            const int kc = ks * 4 + lg;
            bf16x8 a[4], b[4];
#pragma unroll
            for (int i = 0; i < 4; ++i)
                a[i] = *(const bf16x8*)&As[p][rowA0 + 16 * i][(kc ^ xA) * 8];
#pragma unroll
            for (int i = 0; i < 4; ++i)
                b[i] = *(const bf16x8*)&Bs[p][rowB0 + 16 * i][(kc ^ xB) * 8];
#pragma unroll
            for (int i = 0; i < 4; ++i)
#pragma unroll
                for (int j = 0; j < 4; ++j)
                    acc[i][j] = __builtin_amdgcn_mfma_f32_16x16x32_bf16(a[i], b[j], acc[i][j], 0, 0, 0);
        }
        __builtin_amdgcn_s_barrier();   // all waves done reading buf p before it's restaged
    }

    // epilogue: C/D frag mapping col=lane&15 (N dim), row=(lane>>4)*4+reg (M dim)
    const int col  = bn0 + wc * 64 + lr;
    const int row0 = bm0 + wr * 64 + lg * 4;
#pragma unroll
    for (int i = 0; i < 4; ++i) {
#pragma unroll
        for (int j = 0; j < 4; ++j) {
#pragma unroll
            for (int rg = 0; rg < 4; ++rg) {
                atomicAdd(&out[(size_t)(row0 + i * 16 + rg) * OUT_F + col + j * 16],
                          acc[i][j][rg]);
            }
        }
    }
#undef STAGE
}

extern "C" void kernel_launch(void* const* d_in, const int* in_sizes, int n_in,
                              void* d_out, int out_size, void* d_ws, size_t ws_size,
                              hipStream_t stream) {
    const float* x    = (const float*)d_in[0];   // (512, 4096) f32
    const float* wv   = (const float*)d_in[1];   // (nnz,) f32
    const float* bias = (const float*)d_in[2];   // (4096,) f32
    const int*   idx  = (const int*)d_in[3];     // (2, nnz) int32: rows then cols
    const int nnz = in_sizes[1];
    const int* rows = idx;
    const int* cols = idx + nnz;
    float* out = (float*)d_out;

    // workspace layout (16 B aligned chunks)
    char* ws = (char*)d_ws;
    __hip_bfloat16* Wb = (__hip_bfloat16*)ws; ws += (size_t)OUT_F * IN_F * sizeof(__hip_bfloat16); // 32 MB
    __hip_bfloat16* xb = (__hip_bfloat16*)ws; ws += (size_t)BATCH * IN_F * sizeof(__hip_bfloat16); // 4 MB
    int* counts = (int*)ws;                   ws += (size_t)OUT_F * sizeof(int);                   // 16 KB
    unsigned* pairs = (unsigned*)ws;          // OUT_F * CAP * 4 B (~3.4 MB)

    // 1) bucket entries by row (packed 4 B: bf16 weight | col)
    hipMemsetAsync((void*)counts, 0, OUT_F * sizeof(int), stream);
    int nthreads = (nnz + 3) / 4;
    int nb = (nthreads + 255) / 256;
    scatter_pairs_kernel<<<nb, 256, 0, stream>>>(rows, cols, wv, nnz, counts, pairs);

    // 2) densify W (sums duplicates via LDS atomics; writes zeros everywhere else)
    densify_rows_kernel<<<OUT_F, 256, 0, stream>>>(pairs, counts, Wb);

    // 3) x -> bf16, and out <- bias broadcast (for the atomic epilogue)
    convert_bias_kernel<<<(2 * BATCH * IN_F / 4) / 256, 256, 0, stream>>>(x, xb, bias, out);

    // 4) dense MFMA GEMM, K-split=4, counted-vmcnt pipeline, atomicAdd into out
    gemm_acc_kernel<<<NWG, 256, 0, stream>>>(xb, Wb, out);
}

// Round 9
// 88.976 us; speedup vs baseline: 1.2480x; 1.2480x over previous
//
#include <hip/hip_runtime.h>
#include <hip/hip_bf16.h>

#define BATCH  512
#define IN_F   4096
#define OUT_F  4096
#define CAP    208     // bucket capacity; Poisson(122), overflow prob ~1e-11/row
#define CSTR   16      // counts stride (ints): 1 counter per 64-B line (atomic contention fix)

typedef __attribute__((ext_vector_type(8))) short bf16x8;   // 8 bf16 = 4 VGPR (MFMA A/B frag)
typedef __attribute__((ext_vector_type(4))) float f32x4;    // MFMA C/D frag

// bf16 round-to-nearest-even bits from fp32
__device__ __forceinline__ unsigned bf16_bits(float f) {
    unsigned u = __float_as_uint(f);
    return (u + 0x7FFFu + ((u >> 16) & 1u)) >> 16;
}

// ---------------- 0) convert x fp32 -> bf16  +  init out with bias  +  zero counts ----------------
__global__ void convert_bias_kernel(const float* __restrict__ x, __hip_bfloat16* __restrict__ xb,
                                    const float* __restrict__ bias, float* __restrict__ out,
                                    int* __restrict__ counts) {
    const int NC = BATCH * IN_F / 4;      // x convert threads (float4 each)
    const int NB = BATCH * OUT_F / 4;     // bias-init threads (float4 each)
    int i = blockIdx.x * blockDim.x + threadIdx.x;
    if (i < NC) {
        float4 v = ((const float4*)x)[i];
        unsigned lo = bf16_bits(v.x) | (bf16_bits(v.y) << 16);
        unsigned hi = bf16_bits(v.z) | (bf16_bits(v.w) << 16);
        ((uint2*)xb)[i] = make_uint2(lo, hi);
    } else if (i < NC + NB) {
        int j = i - NC;                                   // indexes out as float4
        ((float4*)out)[j] = ((const float4*)bias)[j & (OUT_F / 4 - 1)];
    } else if (i < NC + NB + OUT_F) {
        counts[(i - NC - NB) * CSTR] = 0;                 // one counter per line
    }
}

// ---------------- 1) scatter entries into fixed-capacity row buckets ----------------
// packed[r*CAP + k] = (bf16(w) << 16) | col   (col fits 12 bits)
__global__ void scatter_pairs_kernel(const int* __restrict__ rows,
                                     const int* __restrict__ cols,
                                     const float* __restrict__ w,
                                     int nnz,
                                     int* __restrict__ counts,
                                     unsigned* __restrict__ pairs) {
    int i = blockIdx.x * blockDim.x + threadIdx.x;
    int i4 = i * 4;
    if (i4 + 4 <= nnz) {
        int4   r  = ((const int4*)rows)[i];
        int4   c  = ((const int4*)cols)[i];
        float4 wv = ((const float4*)w)[i];
        int p0 = atomicAdd(&counts[r.x * CSTR], 1);
        if (p0 < CAP) pairs[(size_t)r.x * CAP + p0] = (bf16_bits(wv.x) << 16) | (unsigned)c.x;
        int p1 = atomicAdd(&counts[r.y * CSTR], 1);
        if (p1 < CAP) pairs[(size_t)r.y * CAP + p1] = (bf16_bits(wv.y) << 16) | (unsigned)c.y;
        int p2 = atomicAdd(&counts[r.z * CSTR], 1);
        if (p2 < CAP) pairs[(size_t)r.z * CAP + p2] = (bf16_bits(wv.z) << 16) | (unsigned)c.z;
        int p3 = atomicAdd(&counts[r.w * CSTR], 1);
        if (p3 < CAP) pairs[(size_t)r.w * CAP + p3] = (bf16_bits(wv.w) << 16) | (unsigned)c.w;
    } else {
        for (int j = i4; j < nnz; ++j) {
            int rr = rows[j];
            int pp = atomicAdd(&counts[rr * CSTR], 1);
            if (pp < CAP) pairs[(size_t)rr * CAP + pp] = (bf16_bits(w[j]) << 16) | (unsigned)cols[j];
        }
    }
}

// ---------------- 2) densify: one block per output row -> bf16 dense W (N,K) ----------------
__global__ __launch_bounds__(256) void densify_rows_kernel(const unsigned* __restrict__ pairs,
                                                           const int* __restrict__ counts,
                                                           __hip_bfloat16* __restrict__ Wb) {
    __shared__ __align__(16) float row[IN_F];   // 16 KB
    const int r = blockIdx.x;
    const int t = threadIdx.x;
    const float4 z = make_float4(0.f, 0.f, 0.f, 0.f);
#pragma unroll
    for (int k = 0; k < IN_F / 4 / 256; ++k)
        ((float4*)row)[t + k * 256] = z;
    __syncthreads();
    int cnt = counts[r * CSTR];
    if (cnt > CAP) cnt = CAP;
    const unsigned* bucket = pairs + (size_t)r * CAP;
    for (int j = t; j < cnt; j += 256) {
        unsigned p = bucket[j];
        atomicAdd(&row[p & 0xFFFu], __uint_as_float(p & 0xFFFF0000u));
    }
    __syncthreads();
    unsigned* dst = (unsigned*)(Wb + (size_t)r * IN_F);
#pragma unroll
    for (int k = 0; k < (IN_F / 2) / 256; ++k) {
        int ui = t + k * 256;
        unsigned lo = bf16_bits(row[ui * 2]);
        unsigned hi = bf16_bits(row[ui * 2 + 1]);
        dst[ui] = lo | (hi << 16);
    }
}

// ---------------- 3) GEMM: out[b,n] += sum_k xb[b,k]*Wb[n,k]  (K-split=4) ----------------
// (byte-identical structure to round 8 -- control variable for the scatter fix)
#define BM  128
#define BN  128
#define BKT 64
#define KSPLIT 4
#define KH   (IN_F / KSPLIT)            // 1024
#define NKTH (KH / BKT)                 // 16
#define NWG  ((BATCH / BM) * (OUT_F / BN) * KSPLIT)   // 512

__global__ __launch_bounds__(256) void gemm_acc_kernel(
    const __hip_bfloat16* __restrict__ xb,   // (512, 4096) row-major
    const __hip_bfloat16* __restrict__ Wb,   // (4096, 4096) = (N, K) row-major
    float* __restrict__ out) {               // (512, 4096) fp32, pre-filled with bias

    __shared__ __align__(16) __hip_bfloat16 As[2][BM][BKT];   // 32 KB
    __shared__ __align__(16) __hip_bfloat16 Bs[2][BN][BKT];   // 32 KB

    const int xcd   = blockIdx.x & 7;
    const int local = blockIdx.x >> 3;        // 0..63
    const int ksp   = local & 3;
    const int tile  = xcd * 16 + (local >> 2); // 0..127
    const int bm0   = (tile & 3) * BM;
    const int bn0   = (tile >> 2) * BN;
    const size_t k0 = (size_t)ksp * KH;

    const int t  = threadIdx.x;
    const int l  = t & 63;
    const int w  = t >> 6;
    const int wr = w >> 1;        // wave row 0..1 (64-row strip)
    const int wc = w & 1;         // wave col 0..1 (64-col strip)
    const int lr = l & 15;        // frag lane
    const int lg = l >> 4;        // k-group 0..3

    f32x4 acc[4][4] = {};

#define STAGE(p, kt) do {                                                                         \
    _Pragma("unroll")                                                                             \
    for (int j = 0; j < 4; ++j) {                                                                 \
        int q = t + j * 256; int row = q >> 3; int kcg = (q & 7) ^ (row & 7);                     \
        __builtin_amdgcn_global_load_lds(                                                         \
            (const unsigned*)(xb + (size_t)(bm0 + row) * IN_F + k0 + (kt) * BKT + kcg * 8),       \
            (unsigned*)((__hip_bfloat16*)As[p] + q * 8), 16, 0, 0);                               \
    }                                                                                             \
    _Pragma("unroll")                                                                             \
    for (int j = 0; j < 4; ++j) {                                                                 \
        int q = t + j * 256; int row = q >> 3; int kcg = (q & 7) ^ (row & 7);                     \
        __builtin_amdgcn_global_load_lds(                                                         \
            (const unsigned*)(Wb + (size_t)(bn0 + row) * IN_F + k0 + (kt) * BKT + kcg * 8),       \
            (unsigned*)((__hip_bfloat16*)Bs[p] + q * 8), 16, 0, 0);                               \
    }                                                                                             \
} while (0)

    const int rowA0 = wr * 64 + lr;
    const int rowB0 = wc * 64 + lr;
    const int xA = rowA0 & 7;
    const int xB = rowB0 & 7;

    STAGE(0, 0);
    for (int kt = 0; kt < NKTH; ++kt) {
        const int p = kt & 1;
        if (kt + 1 < NKTH) {
            STAGE(p ^ 1, kt + 1);
            asm volatile("s_waitcnt vmcnt(8)" ::: "memory");
        } else {
            asm volatile("s_waitcnt vmcnt(0)" ::: "memory");
        }
        __builtin_amdgcn_s_barrier();

#pragma unroll
        for (int ks = 0; ks < 2; ++ks) {
            const int kc = ks * 4 + lg;
            bf16x8 a[4], b[4];
#pragma unroll
            for (int i = 0; i < 4; ++i)
                a[i] = *(const bf16x8*)&As[p][rowA0 + 16 * i][(kc ^ xA) * 8];
#pragma unroll
            for (int i = 0; i < 4; ++i)
                b[i] = *(const bf16x8*)&Bs[p][rowB0 + 16 * i][(kc ^ xB) * 8];
#pragma unroll
            for (int i = 0; i < 4; ++i)
#pragma unroll
                for (int j = 0; j < 4; ++j)
                    acc[i][j] = __builtin_amdgcn_mfma_f32_16x16x32_bf16(a[i], b[j], acc[i][j], 0, 0, 0);
        }
        __builtin_amdgcn_s_barrier();
    }

    const int col  = bn0 + wc * 64 + lr;
    const int row0 = bm0 + wr * 64 + lg * 4;
#pragma unroll
    for (int i = 0; i < 4; ++i) {
#pragma unroll
        for (int j = 0; j < 4; ++j) {
#pragma unroll
            for (int rg = 0; rg < 4; ++rg) {
                atomicAdd(&out[(size_t)(row0 + i * 16 + rg) * OUT_F + col + j * 16],
                          acc[i][j][rg]);
            }
        }
    }
#undef STAGE
}

extern "C" void kernel_launch(void* const* d_in, const int* in_sizes, int n_in,
                              void* d_out, int out_size, void* d_ws, size_t ws_size,
                              hipStream_t stream) {
    const float* x    = (const float*)d_in[0];   // (512, 4096) f32
    const float* wv   = (const float*)d_in[1];   // (nnz,) f32
    const float* bias = (const float*)d_in[2];   // (4096,) f32
    const int*   idx  = (const int*)d_in[3];     // (2, nnz) int32: rows then cols
    const int nnz = in_sizes[1];
    const int* rows = idx;
    const int* cols = idx + nnz;
    float* out = (float*)d_out;

    // workspace layout (16 B aligned chunks)
    char* ws = (char*)d_ws;
    __hip_bfloat16* Wb = (__hip_bfloat16*)ws; ws += (size_t)OUT_F * IN_F * sizeof(__hip_bfloat16); // 32 MB
    __hip_bfloat16* xb = (__hip_bfloat16*)ws; ws += (size_t)BATCH * IN_F * sizeof(__hip_bfloat16); // 4 MB
    int* counts = (int*)ws;                   ws += (size_t)OUT_F * CSTR * sizeof(int);            // 256 KB
    unsigned* pairs = (unsigned*)ws;          // OUT_F * CAP * 4 B (~3.4 MB)

    // 0) x->bf16, out<-bias, counts<-0 (one kernel, no separate memset dispatch)
    const int NTOT = BATCH * IN_F / 4 + BATCH * OUT_F / 4 + OUT_F;
    convert_bias_kernel<<<(NTOT + 255) / 256, 256, 0, stream>>>(x, xb, bias, out, counts);

    // 1) bucket entries by row (packed 4 B: bf16 weight | col); padded counters
    int nthreads = (nnz + 3) / 4;
    int nb = (nthreads + 255) / 256;
    scatter_pairs_kernel<<<nb, 256, 0, stream>>>(rows, cols, wv, nnz, counts, pairs);

    // 2) densify W (sums duplicates via LDS atomics; writes zeros everywhere else)
    densify_rows_kernel<<<OUT_F, 256, 0, stream>>>(pairs, counts, Wb);

    // 3) dense MFMA GEMM, K-split=4, counted-vmcnt pipeline, atomicAdd into out
    gemm_acc_kernel<<<NWG, 256, 0, stream>>>(xb, Wb, out);
}